// Round 1
// baseline (232.018 us; speedup 1.0000x reference)
//
#include <hip/hip_runtime.h>

#define NT 1024
#define NS 2048
#define NH 32

// One thread per (s, h). Each 32-thread group owns one site s:
//   - state role: lane = h (S, H in registers, shfl reduction for Y)
//   - load role:  lane = time-offset within a 32-step chunk (full-wave acos prep)
// Chunk data staged in wave-private LDS (no barriers), broadcast-read per step.
__global__ __launch_bounds__(256, 1)
void waternet_kernel(const float* __restrict__ P,
                     const float* __restrict__ T1,
                     const float* __restrict__ T2,
                     const float* __restrict__ E,
                     const float* __restrict__ w,
                     float* __restrict__ Y)
{
    const int tid  = threadIdx.x;
    const int lane = tid & 31;   // h index AND time-offset for loads
    const int grp  = tid >> 5;   // s-group within block (0..7)

    // XCD-contiguous s mapping: blocks with bid%8==x (same XCD under round-robin
    // dispatch) cover a contiguous 256-site slab -> 64B lines shared within one L2.
    const int bid    = blockIdx.x;
    const int sChunk = (bid & 7) * 32 + (bid >> 3);   // bijective [0,256)
    const int s      = sChunk * 8 + grp;              // [0, 2048)

    // ---- per-h gate weights (one-time) ----
    const float wm = w[lane];
    const float we = w[NH + lane];
    const float wo = w[2 * NH + lane];
    const float wa = w[3 * NH + lane];

    const float gm = expf(wm) + 1.0f;
    const float ge = 1.0f / (1.0f + expf(-we));
    const float go = 1.0f / (1.0f + expf(-wo));

    // softmax over the 32 lanes of this group (xor masks <32 stay in-half)
    float mx = wa;
    #pragma unroll
    for (int o = 16; o; o >>= 1) mx = fmaxf(mx, __shfl_xor(mx, o));
    float ea = expf(wa - mx);
    float ssum = ea;
    #pragma unroll
    for (int o = 16; o; o >>= 1) ssum += __shfl_xor(ssum, o);
    const float ga  = ea / ssum;
    const float go1 = 1.0f - go;   // H' = H3*(1-go)
    const float gq  = go * ga;     // y  = H3*go*ga

    float S  = 0.0f;
    float Hs = 0.0f;

    __shared__ float4 stage[8][32];   // per-group chunk staging {Ta+, Ps, Pl, E}

    // prefetch chunk 0 (lane-transposed: lane l loads row t = l)
    size_t base = (size_t)lane * NS + s;
    float p0 = P[base], a0 = T1[base], b0 = T2[base], e0 = E[base];

    for (int c = 0; c < 32; ++c) {
        const float p = p0, ta = a0, tb = b0, ee = e0;
        if (c < 31) {   // software prefetch next chunk (covered by inner loop)
            size_t nb = base + (size_t)(c + 1) * 32 * NS;
            p0 = P[nb]; a0 = T1[nb]; b0 = T2[nb]; e0 = E[nb];
        }

        // ---- per-(t,s) prep, full-wave (lane = time offset) ----
        float sum   = ta + tb;            // 2*Ta
        float diff  = tb - ta;            // > 0 guaranteed
        float ratio = sum / diff;
        ratio = fminf(fmaxf(ratio, -1.0f), 1.0f);
        float rP = 1.0f - acosf(ratio) * (1.0f / 3.1415f);
        if (ta >= 0.0f) rP = 1.0f;
        if (tb <= 0.0f) rP = 0.0f;
        const float Pl  = rP * p;
        const float Ps  = p - Pl;                    // (1-rP)*P
        const float TaP = fmaxf(sum * 0.5f, 0.0f);   // max(Ta,0); gm>0 so max(Ta*gm,0)=TaP*gm
        stage[grp][lane] = make_float4(TaP, Ps, Pl, ee);
        // wave-private producer/consumer: in-order DS ops within a wave, no barrier

        const int trow = c * 32;
        #pragma unroll
        for (int k = 0; k < 32; ++k) {
            const float4 x  = stage[grp][k];         // same-addr broadcast read
            const float bm  = x.x * gm;              // max(Ta*gm, 0)
            const float Sm  = fminf(S, bm);
            const float Sp  = S + x.y;               // S + Ps
            const float h1  = Hs + Sm;
            const float h2  = h1 + x.z;              // + Pl
            const float h3  = fmaxf(fmaf(-x.w, ge, h2), 0.0f);  // - E*ge, relu
            S  = Sp - Sm;
            Hs = h3 * go1;
            float y = h3 * gq;
            y += __shfl_xor(y, 16);
            y += __shfl_xor(y, 8);
            y += __shfl_xor(y, 4);
            y += __shfl_xor(y, 2);
            y += __shfl_xor(y, 1);
            if (lane == 0) Y[(size_t)(trow + k) * NS + s] = y;
        }
    }
}

extern "C" void kernel_launch(void* const* d_in, const int* in_sizes, int n_in,
                              void* d_out, int out_size, void* d_ws, size_t ws_size,
                              hipStream_t stream) {
    const float* P  = (const float*)d_in[0];
    const float* T1 = (const float*)d_in[1];
    const float* T2 = (const float*)d_in[2];
    const float* E  = (const float*)d_in[3];
    const float* w  = (const float*)d_in[4];
    float* Y = (float*)d_out;

    waternet_kernel<<<dim3(256), dim3(256), 0, stream>>>(P, T1, T2, E, w, Y);
}

// Round 2
// 53.929 us; speedup vs baseline: 4.3023x; 4.3023x over previous
//
#include <hip/hip_runtime.h>

#define NT 1024
#define NS 2048
#define NH 32

// One thread per (s, h). 32-lane group per site s:
//   - state role: lane = h (S, H in registers)
//   - load role:  lane = time-offset within a 32-step chunk (full-wave acos prep)
// Reduction over h is DEFERRED: per step each lane dumps h3*gq to LDS;
// once per 32-step chunk, a padded transpose-read + pipelined sum produces
// 32 outputs. Removes the 5-dependent-shuffle chain from the sequential path.
__global__ __launch_bounds__(256, 1)
void waternet_kernel(const float* __restrict__ P,
                     const float* __restrict__ T1,
                     const float* __restrict__ T2,
                     const float* __restrict__ E,
                     const float* __restrict__ w,
                     float* __restrict__ Y)
{
    const int tid  = threadIdx.x;
    const int lane = tid & 31;   // h index AND time-offset for loads
    const int grp  = tid >> 5;   // s-group within block (0..7)

    // XCD-contiguous s mapping (round-robin dispatch: bid%8 = XCD)
    const int bid    = blockIdx.x;
    const int sChunk = (bid & 7) * 32 + (bid >> 3);   // bijective [0,256)
    const int s      = sChunk * 8 + grp;              // [0, 2048)

    // ---- per-h gate weights (one-time) ----
    const float wm = w[lane];
    const float we = w[NH + lane];
    const float wo = w[2 * NH + lane];
    const float wa = w[3 * NH + lane];

    const float gm = expf(wm) + 1.0f;
    const float ge = 1.0f / (1.0f + expf(-we));
    const float go = 1.0f / (1.0f + expf(-wo));

    // softmax over the 32 lanes of this group (xor masks <32 stay in-half)
    float mx = wa;
    #pragma unroll
    for (int o = 16; o; o >>= 1) mx = fmaxf(mx, __shfl_xor(mx, o));
    float ea = expf(wa - mx);
    float ssum = ea;
    #pragma unroll
    for (int o = 16; o; o >>= 1) ssum += __shfl_xor(ssum, o);
    const float ga  = ea / ssum;
    const float go1 = 1.0f - go;   // H' = h3*(1-go)
    const float gq  = go * ga;     // y-contrib = h3*go*ga

    float S  = 0.0f;
    float Hs = 0.0f;

    __shared__ float4 stage[8][32];       // per-group chunk inputs {Ta+, Ps, Pl, E}
    __shared__ float  ytmp[8][32][33];    // per-group y contribs, +1 pad for transpose

    // prefetch chunk 0 (lane-transposed: lane l loads row t = l)
    size_t base = (size_t)lane * NS + s;
    float p0 = P[base], a0 = T1[base], b0 = T2[base], e0 = E[base];

    for (int c = 0; c < 32; ++c) {
        const float p = p0, ta = a0, tb = b0, ee = e0;
        if (c < 31) {   // software prefetch next chunk (covered by inner loop)
            size_t nb = base + (size_t)(c + 1) * 32 * NS;
            p0 = P[nb]; a0 = T1[nb]; b0 = T2[nb]; e0 = E[nb];
        }

        // ---- per-(t,s) prep, full-wave (lane = time offset) ----
        float sum   = ta + tb;            // 2*Ta
        float diff  = tb - ta;            // > 0 guaranteed
        float ratio = sum / diff;
        ratio = fminf(fmaxf(ratio, -1.0f), 1.0f);
        float rP = 1.0f - acosf(ratio) * (1.0f / 3.1415f);
        if (ta >= 0.0f) rP = 1.0f;
        if (tb <= 0.0f) rP = 0.0f;
        const float Pl  = rP * p;
        const float Ps  = p - Pl;                    // (1-rP)*P
        const float TaP = fmaxf(sum * 0.5f, 0.0f);   // gm>0 so max(Ta*gm,0)=TaP*gm
        stage[grp][lane] = make_float4(TaP, Ps, Pl, ee);
        // wave-private producer/consumer: DS ops are in-order within a wave

        #pragma unroll
        for (int k = 0; k < 32; ++k) {
            const float4 x  = stage[grp][k];          // same-addr broadcast read
            const float bm  = x.x * gm;               // off-chain
            const float Sm  = fminf(S, bm);
            const float add = x.z + Sm;               // Pl + Sm
            const float h3  = fmaxf(fmaf(-x.w, ge, Hs + add), 0.0f);
            S  = (S + x.y) - Sm;
            Hs = h3 * go1;
            ytmp[grp][k][lane] = h3 * gq;             // off-chain ds_write
        }

        // ---- deferred reduction: lane l sums contribs for t = c*32 + l ----
        float a0s = 0.0f, a1s = 0.0f, a2s = 0.0f, a3s = 0.0f;
        #pragma unroll
        for (int k = 0; k < 32; k += 4) {             // 4 independent chains
            a0s += ytmp[grp][lane][k + 0];
            a1s += ytmp[grp][lane][k + 1];
            a2s += ytmp[grp][lane][k + 2];
            a3s += ytmp[grp][lane][k + 3];
        }
        Y[(size_t)(c * 32 + lane) * NS + s] = (a0s + a1s) + (a2s + a3s);
    }
}

extern "C" void kernel_launch(void* const* d_in, const int* in_sizes, int n_in,
                              void* d_out, int out_size, void* d_ws, size_t ws_size,
                              hipStream_t stream) {
    const float* P  = (const float*)d_in[0];
    const float* T1 = (const float*)d_in[1];
    const float* T2 = (const float*)d_in[2];
    const float* E  = (const float*)d_in[3];
    const float* w  = (const float*)d_in[4];
    float* Y = (float*)d_out;

    waternet_kernel<<<dim3(256), dim3(256), 0, stream>>>(P, T1, T2, E, w, Y);
}

// Round 3
// 47.750 us; speedup vs baseline: 4.8590x; 1.1294x over previous
//
#include <hip/hip_runtime.h>

#define NT 1024
#define NS 2048
#define NH 32
#define PF 8   // rolling register prefetch depth (steps ahead)

// One thread per (s, h). 32-lane group per site s:
//   - state role: lane = h (S, H in registers)
//   - load role:  lane = time-offset within a 32-step chunk (full-wave acos prep)
// Software pipeline:
//   globals loaded 2 chunks ahead -> prep for chunk c+1 at top of chunk c
//   -> double-buffered stage LDS -> 8-deep rolling register prefetch (xbuf)
//   -> pure-VALU state chain. y reduction deferred to chunk end via LDS transpose.
__global__ __launch_bounds__(256, 1)
void waternet_kernel(const float* __restrict__ P,
                     const float* __restrict__ T1,
                     const float* __restrict__ T2,
                     const float* __restrict__ E,
                     const float* __restrict__ w,
                     float* __restrict__ Y)
{
    const int tid  = threadIdx.x;
    const int lane = tid & 31;   // h index AND time-offset for loads
    const int grp  = tid >> 5;   // s-group within block (0..7)

    // XCD-contiguous s mapping (round-robin dispatch: bid%8 = XCD)
    const int bid    = blockIdx.x;
    const int sChunk = (bid & 7) * 32 + (bid >> 3);   // bijective [0,256)
    const int s      = sChunk * 8 + grp;              // [0, 2048)

    // ---- per-h gate weights (one-time) ----
    const float wm = w[lane];
    const float we = w[NH + lane];
    const float wo = w[2 * NH + lane];
    const float wa = w[3 * NH + lane];

    const float gm = expf(wm) + 1.0f;
    const float ge = 1.0f / (1.0f + expf(-we));
    const float go = 1.0f / (1.0f + expf(-wo));

    float mx = wa;
    #pragma unroll
    for (int o = 16; o; o >>= 1) mx = fmaxf(mx, __shfl_xor(mx, o));
    float ea = expf(wa - mx);
    float ssum = ea;
    #pragma unroll
    for (int o = 16; o; o >>= 1) ssum += __shfl_xor(ssum, o);
    const float ga  = ea / ssum;
    const float go1 = 1.0f - go;   // H' = h3*(1-go)
    const float gq  = go * ga;     // y-contrib = h3*go*ga

    float S  = 0.0f;
    float Hs = 0.0f;

    __shared__ float4 stage[2][8][32];    // double-buffered chunk inputs {TaP, Ps, Pl, E}
    __shared__ float  ytmp[8][32][33];    // y contribs, +1 pad for conflict-free transpose

    // lane-transposed global loads: lane l covers time row (chunk*32 + l)
    size_t base = (size_t)lane * NS + s;
    float p0 = P[base], a0 = T1[base], b0 = T2[base], e0 = E[base];
    size_t bn = base + (size_t)32 * NS;
    float pg = P[bn], ag = T1[bn], bg = T2[bn], eg = E[bn];   // chunk 1

    auto prep = [&](float p, float ta, float tb, float ee, int buf) {
        float sum   = ta + tb;                       // 2*Ta
        float ratio = sum / (tb - ta);               // tb>ta guaranteed
        ratio = fminf(fmaxf(ratio, -1.0f), 1.0f);
        float rP = 1.0f - acosf(ratio) * (1.0f / 3.1415f);
        if (ta >= 0.0f) rP = 1.0f;
        if (tb <= 0.0f) rP = 0.0f;
        float Pl  = rP * p;
        float Ps  = p - Pl;                          // (1-rP)*P
        float TaP = fmaxf(sum * 0.5f, 0.0f);         // gm>0: max(Ta*gm,0)=TaP*gm
        stage[buf][grp][lane] = make_float4(TaP, Ps, Pl, ee);
    };

    prep(p0, a0, b0, e0, 0);   // chunk 0 -> buffer 0

    // rolling prefetch buffers (gates folded in at refill, off the critical path)
    float xx[PF], xy[PF], xw[PF];   // bm = TaP*gm, Ps, pw = Pl - E*ge
    #pragma unroll
    for (int j = 0; j < PF; ++j) {
        float4 x = stage[0][grp][j];
        xx[j] = x.x * gm;
        xy[j] = x.y;
        xw[j] = x.z - x.w * ge;
    }

    #pragma unroll 2
    for (int c = 0; c < 32; ++c) {
        if (c < 31) prep(pg, ag, bg, eg, (c + 1) & 1);   // producer one chunk ahead
        if (c < 30) {                                     // globals two chunks ahead
            size_t nb = base + (size_t)(c + 2) * 32 * NS;
            pg = P[nb]; ag = T1[nb]; bg = T2[nb]; eg = E[nb];
        }

        #pragma unroll
        for (int k = 0; k < 32; ++k) {
            const int sl = k & (PF - 1);
            const float bm = xx[sl], Ps = xy[sl], pw = xw[sl];
            // sequential chain: min -> add -> max -> mul (~16 cyc)
            const float Sm = fminf(S, bm);
            const float t  = Hs + pw;                 // off the Sm chain
            const float Sn = (S + Ps) - Sm;
            const float h3 = fmaxf(t + Sm, 0.0f);
            S  = Sn;
            Hs = h3 * go1;
            ytmp[grp][k][lane] = h3 * gq;             // off-chain ds_write

            // refill slot with step k+PF (crosses into next chunk's buffer)
            const int idx = k + PF;
            const int buf = (c + (idx >> 5)) & 1;     // compile-time after unroll-2
            float4 x = stage[buf][grp][idx & 31];     // ds_read issued PF steps early
            xx[sl] = x.x * gm;
            xy[sl] = x.y;
            xw[sl] = x.z - x.w * ge;
        }

        // ---- deferred reduction: lane l sums h-contribs for t = c*32 + l ----
        float r0 = 0.f, r1 = 0.f, r2 = 0.f, r3 = 0.f;
        #pragma unroll
        for (int k = 0; k < 32; k += 4) {             // 4 independent add chains
            r0 += ytmp[grp][lane][k + 0];
            r1 += ytmp[grp][lane][k + 1];
            r2 += ytmp[grp][lane][k + 2];
            r3 += ytmp[grp][lane][k + 3];
        }
        Y[(size_t)(c * 32 + lane) * NS + s] = (r0 + r1) + (r2 + r3);
    }
}

extern "C" void kernel_launch(void* const* d_in, const int* in_sizes, int n_in,
                              void* d_out, int out_size, void* d_ws, size_t ws_size,
                              hipStream_t stream) {
    const float* P  = (const float*)d_in[0];
    const float* T1 = (const float*)d_in[1];
    const float* T2 = (const float*)d_in[2];
    const float* E  = (const float*)d_in[3];
    const float* w  = (const float*)d_in[4];
    float* Y = (float*)d_out;

    waternet_kernel<<<dim3(256), dim3(256), 0, stream>>>(P, T1, T2, E, w, Y);
}

// Round 5
// 45.736 us; speedup vs baseline: 5.0730x; 1.0440x over previous
//
#include <hip/hip_runtime.h>

#define NT 1024
#define NS 2048
#define NH 32

// One thread per (s, h). 32-lane group (half-wave) per site s:
//   - state role: lane = h (S, H in registers)
//   - load role:  lane = time-offset within a 32-step chunk (full-wave acos prep)
// Chunk pipeline (wave-private LDS, no barriers):
//   top of chunk c: [32x ds_read_b128: whole stage chunk -> 128 VGPRs]
//                   [prep chunk c+1 -> stage[(c+1)&1]]
//                   [global loads chunk c+2 issued]
//                   [deferred y-reduction of chunk c-1 from ytmp[(c-1)&1]]
//   then 32 pure-VALU steps writing y-contribs to ytmp[c&1].
// ytmp is DOUBLE-BUFFERED so the reduction reads and the step writes touch
// provably disjoint memory -> no diagonal alias hazard (R4's correctness bug).
__global__ __launch_bounds__(256, 1)
void waternet_kernel(const float* __restrict__ P,
                     const float* __restrict__ T1,
                     const float* __restrict__ T2,
                     const float* __restrict__ E,
                     const float* __restrict__ w,
                     float* __restrict__ Y)
{
    const int tid  = threadIdx.x;
    const int lane = tid & 31;   // h index AND time-offset for loads
    const int grp  = tid >> 5;   // s-group within block (0..7)

    // XCD-contiguous s mapping (round-robin dispatch: bid%8 = XCD)
    const int bid    = blockIdx.x;
    const int sChunk = (bid & 7) * 32 + (bid >> 3);   // bijective [0,256)
    const int s      = sChunk * 8 + grp;              // [0, 2048)

    // ---- per-h gate weights (one-time) ----
    const float wm = w[lane];
    const float we = w[NH + lane];
    const float wo = w[2 * NH + lane];
    const float wa = w[3 * NH + lane];

    const float gm = expf(wm) + 1.0f;
    const float ge = 1.0f / (1.0f + expf(-we));
    const float go = 1.0f / (1.0f + expf(-wo));

    float mx = wa;
    #pragma unroll
    for (int o = 16; o; o >>= 1) mx = fmaxf(mx, __shfl_xor(mx, o));
    float ea = expf(wa - mx);
    float ssum = ea;
    #pragma unroll
    for (int o = 16; o; o >>= 1) ssum += __shfl_xor(ssum, o);
    const float ga  = ea / ssum;
    const float go1 = 1.0f - go;   // H' = h3*(1-go)
    const float gq  = go * ga;     // y-contrib = h3*go*ga

    float S  = 0.0f;
    float Hs = 0.0f;

    __shared__ float4 stage[2][8][32];       // dbuf chunk inputs {TaP, Ps, Pl, E}
    __shared__ float  ytmp[2][8][32][33];    // dbuf y contribs [buf][grp][step][h], +1 pad

    // lane-transposed global loads: lane l covers time row (chunk*32 + l)
    size_t base = (size_t)lane * NS + s;
    float p0 = P[base], a0 = T1[base], b0 = T2[base], e0 = E[base];
    size_t bn = base + (size_t)32 * NS;
    float pg = P[bn], ag = T1[bn], bg = T2[bn], eg = E[bn];   // chunk 1

    auto prep = [&](float p, float ta, float tb, float ee, int buf) {
        float sum   = ta + tb;                       // 2*Ta
        float ratio = sum / (tb - ta);               // tb>ta guaranteed
        ratio = fminf(fmaxf(ratio, -1.0f), 1.0f);
        float rP = 1.0f - acosf(ratio) * (1.0f / 3.1415f);
        if (ta >= 0.0f) rP = 1.0f;
        if (tb <= 0.0f) rP = 0.0f;
        float Pl  = rP * p;
        float Ps  = p - Pl;                          // (1-rP)*P
        float TaP = fmaxf(sum * 0.5f, 0.0f);         // gm>0: max(Ta*gm,0)=TaP*gm
        stage[buf][grp][lane] = make_float4(TaP, Ps, Pl, ee);
    };

    prep(p0, a0, b0, e0, 0);   // chunk 0 -> buffer 0

    for (int c = 0; c < 32; ++c) {
        // ---- bulk-load this chunk's stage into registers (32x ds_read_b128) ----
        float4 x[32];
        #pragma unroll
        for (int j = 0; j < 32; ++j) x[j] = stage[c & 1][grp][j];

        // ---- producer for chunk c+1 (covers the read latency with VALU) ----
        if (c < 31) prep(pg, ag, bg, eg, (c + 1) & 1);
        if (c < 30) {                                 // globals two chunks ahead
            size_t nb = base + (size_t)(c + 2) * 32 * NS;
            pg = P[nb]; ag = T1[nb]; bg = T2[nb]; eg = E[nb];
        }

        // ---- deferred y-reduction for chunk c-1 (other ytmp buffer) ----
        if (c > 0) {
            const float* yr = &ytmp[(c - 1) & 1][grp][lane][0];
            float r0 = 0.f, r1 = 0.f, r2 = 0.f, r3 = 0.f;
            #pragma unroll
            for (int k = 0; k < 32; k += 4) {         // 4 independent add chains
                r0 += yr[k + 0];
                r1 += yr[k + 1];
                r2 += yr[k + 2];
                r3 += yr[k + 3];
            }
            Y[(size_t)((c - 1) * 32 + lane) * NS + s] = (r0 + r1) + (r2 + r3);
        }

        // ---- 32 pure-VALU steps from registers ----
        float* yw = &ytmp[c & 1][grp][0][lane];
        #pragma unroll
        for (int k = 0; k < 32; ++k) {
            const float4 xx = x[k];
            const float bm = xx.x * gm;                    // off-chain
            const float pw = fmaf(-xx.w, ge, xx.z);        // Pl - E*ge, off-chain
            const float Sm = fminf(S, bm);
            const float Sp = S + xx.y;                     // parallel to Sm
            const float h3 = fmaxf(Hs + (pw + Sm), 0.0f);
            S  = Sp - Sm;
            Hs = h3 * go1;
            yw[k * 33] = h3 * gq;                          // off-chain ds_write
        }

        asm volatile("" ::: "memory");   // pin DS ops to their iteration
    }

    // ---- epilogue: reduction for chunk 31 (buffer 1) ----
    {
        const float* yr = &ytmp[1][grp][lane][0];
        float r0 = 0.f, r1 = 0.f, r2 = 0.f, r3 = 0.f;
        #pragma unroll
        for (int k = 0; k < 32; k += 4) {
            r0 += yr[k + 0];
            r1 += yr[k + 1];
            r2 += yr[k + 2];
            r3 += yr[k + 3];
        }
        Y[(size_t)(31 * 32 + lane) * NS + s] = (r0 + r1) + (r2 + r3);
    }
}

extern "C" void kernel_launch(void* const* d_in, const int* in_sizes, int n_in,
                              void* d_out, int out_size, void* d_ws, size_t ws_size,
                              hipStream_t stream) {
    const float* P  = (const float*)d_in[0];
    const float* T1 = (const float*)d_in[1];
    const float* T2 = (const float*)d_in[2];
    const float* E  = (const float*)d_in[3];
    const float* w  = (const float*)d_in[4];
    float* Y = (float*)d_out;

    waternet_kernel<<<dim3(256), dim3(256), 0, stream>>>(P, T1, T2, E, w, Y);
}